// Round 21
// baseline (984.099 us; speedup 1.0000x reference)
//
#include <hip/hip_runtime.h>
#include <cstddef>

#define BB    16
#define CDIM  512
#define HWN   784
#define KC    2048
#define NR    (BB*HWN)                  // 12544 rows (= 49*256 = 4*3136)
#define ETOT  ((size_t)BB*CDIM*HWN)     // 6422528 elements per tensor
#define NSTRIP 16                       // code strips of 128 (32 half-planes)
#define MARGIN 0.5f                     // exact-recheck margin (~22 sigma)
#define ATSZ  16384                     // A chunk: 256 rows x 64 halves (32KB)
#define INF   3.0e38f
#define BIGI  0x7fffffff

typedef _Float16 hf8 __attribute__((ext_vector_type(8)));
typedef float f32x4 __attribute__((ext_vector_type(4)));

__device__ __forceinline__ void gload_lds16(const void* g, void* l) {
    __builtin_amdgcn_global_load_lds((const __attribute__((address_space(1))) void*)g,
                                     (__attribute__((address_space(3))) void*)l, 16, 0, 0);
}

// ---------------------------------------------------------------- utilities

// head (B,C,HW) -> f rows (fp32) AND fs rows (f16 hi only); zeroes lacc.
__global__ __launch_bounds__(256)
void transpose_head_split(const float* __restrict__ head, float* __restrict__ f,
                          _Float16* __restrict__ fs, float* __restrict__ lacc) {
    __shared__ float tile[32][33];
    int b = blockIdx.z, c0 = blockIdx.y * 32, h0 = blockIdx.x * 32;
    int t = threadIdx.x;
    if (b == 0 && blockIdx.y == 0 && blockIdx.x == 0 && t < 3) lacc[t] = 0.f;
    const float* src = head + (size_t)b * CDIM * HWN;
    {
        int hl = t & 31, cl0 = t >> 5;
#pragma unroll
        for (int it = 0; it < 4; ++it) {
            int cl = cl0 + it * 8;
            int hw = h0 + hl;
            if (hw < HWN) tile[cl][hl] = src[(size_t)(c0 + cl) * HWN + hw];
        }
    }
    __syncthreads();
    float* dst = f + (size_t)b * HWN * CDIM;
    _Float16* dsts = fs + (size_t)b * HWN * CDIM;
    {
        int cl = t & 31, hl0 = t >> 5;
#pragma unroll
        for (int it = 0; it < 4; ++it) {
            int hl = hl0 + it * 8;
            int hw = h0 + hl;
            if (hw < HWN) {
                float v = tile[cl][hl];
                dst[(size_t)hw * CDIM + c0 + cl] = v;
                dsts[(size_t)hw * CDIM + c0 + cl] = (_Float16)v;
            }
        }
    }
}

// codebook fp32 [K][512] -> f16 hi [K][512] + ||row||^2 (one wave per row)
__global__ __launch_bounds__(256)
void split_code_norm(const float* __restrict__ src, _Float16* __restrict__ dst,
                     float* __restrict__ cnorm) {
    int tid = blockIdx.x * 256 + threadIdx.x;        // 8 elems per thread
    int row = tid >> 6, c8 = (tid & 63) * 8;
    const float* p = src + (size_t)row * CDIM + c8;
    float4 v0 = *(const float4*)p, v1 = *(const float4*)(p + 4);
    hf8 hi;
    float x[8] = {v0.x, v0.y, v0.z, v0.w, v1.x, v1.y, v1.z, v1.w};
    float s = 0.f;
#pragma unroll
    for (int j = 0; j < 8; ++j) {
        hi[j] = (_Float16)x[j];
        s += x[j] * x[j];
    }
    *(hf8*)&dst[(size_t)row * CDIM + c8] = hi;
#pragma unroll
    for (int off = 32; off; off >>= 1) s += __shfl_down(s, off);
    if ((threadIdx.x & 63) == 0) cnorm[row] = s;
}

// --------------------------------------------- MFMA coarse argmin (f16 hi, K=512)
// 256 rows x 128 codes per block, 8 waves (4x2 of 64x64). BK=64, 8 chunks.
// SINGLE-buffered A (32KB) + B (16KB) = 48KB LDS -> 3 blocks/CU = 24 waves
// (75% occ): inter-block TLP hides the serial stage latency (the occupancy
// ladder 9->20->37% was the only lever that consistently paid; all schedule
// pipelining at 2 blocks/CU measured null). Serial 2-barrier chunk frame
// (R6-proven hazards). Grid 784 / 768 co-resident = 1.02 generations.
// Emits lean top-2 per (strip, wc-half, row); fp64 recheck in combine_exact.
__global__ __launch_bounds__(512, 6)
void argmin_fast(const _Float16* __restrict__ fs, const _Float16* __restrict__ cs,
                 const float* __restrict__ cnorm, float4* __restrict__ part) {
    __shared__ _Float16 As[ATSZ];        // [256][64] = 32 KB
    __shared__ _Float16 Bs[128 * 64];    // 16 KB

    int t = threadIdx.x;
    int lane = t & 63, w = t >> 6;
    int wr = w >> 1, wc = w & 1;

    // XCD swizzle (R13-proven map)
    int lin = blockIdx.x;
    int swz = (lin & 7) * 98 + (lin >> 3);
    int strip = swz & 15, rowtile = swz >> 4;    // rowtile 0..48
    int rb = rowtile * 256, cb = strip * 128;

    // staging: thread t stages granule (row = p*64 + (t>>3), col-granule t&7);
    // source XOR-swizzled by row&7; LDS dest linear (R18/R19-verified).
    int srow = t >> 3;
    int sgx = (t & 7) ^ (srow & 7);
    const _Float16* pA0 = fs + (size_t)(rb + srow) * CDIM + sgx * 8;
    const _Float16* pA1 = fs + (size_t)(rb + 64 + srow) * CDIM + sgx * 8;
    const _Float16* pA2 = fs + (size_t)(rb + 128 + srow) * CDIM + sgx * 8;
    const _Float16* pA3 = fs + (size_t)(rb + 192 + srow) * CDIM + sgx * 8;
    const _Float16* pB0 = cs + (size_t)(cb + srow) * CDIM + sgx * 8;
    const _Float16* pB1 = cs + (size_t)(cb + 64 + srow) * CDIM + sgx * 8;
    int dd = t * 8;

    // fragment reads: row r wants logical granule ks*4+(lane>>4) at physical
    // granule ^(r&7); (r&7)==(lane&7) since 16 | row-steps (R18/R19-verified).
    int g0 = (lane >> 4) ^ (lane & 7);
    int g1 = g0 ^ 4;
    int aR0 = (wr * 64 + (lane & 15)) * 64 + g0 * 8;
    int aR1 = (wr * 64 + (lane & 15)) * 64 + g1 * 8;
    int bR0 = (wc * 64 + (lane & 15)) * 64 + g0 * 8;
    int bR1 = (wc * 64 + (lane & 15)) * 64 + g1 * 8;

    f32x4 acc[4][4];
#pragma unroll
    for (int m = 0; m < 4; ++m)
#pragma unroll
        for (int n = 0; n < 4; ++n) acc[m][n] = (f32x4)0.f;

    for (int kk = 0; kk < 8; ++kk) {
        int ko = kk * 64;
        // stage chunk kk into the single buffers (prev end-barrier guarantees
        // all waves finished reading chunk kk-1 before any DMA lands here)
        gload_lds16(pA0 + ko, &As[0 * 4096 + dd]);
        gload_lds16(pA1 + ko, &As[1 * 4096 + dd]);
        gload_lds16(pA2 + ko, &As[2 * 4096 + dd]);
        gload_lds16(pA3 + ko, &As[3 * 4096 + dd]);
        gload_lds16(pB0 + ko, &Bs[dd]);
        gload_lds16(pB1 + ko, &Bs[4096 + dd]);
        __syncthreads();                     // drains vmcnt: chunk kk resident
        // ks = 0
        {
            hf8 b0 = *(hf8*)&Bs[bR0];
            hf8 b1 = *(hf8*)&Bs[bR0 + 1024];
            hf8 b2 = *(hf8*)&Bs[bR0 + 2048];
            hf8 b3 = *(hf8*)&Bs[bR0 + 3072];
#pragma unroll
            for (int m = 0; m < 4; ++m) {
                hf8 a = *(hf8*)&As[aR0 + m * 1024];
                acc[m][0] = __builtin_amdgcn_mfma_f32_16x16x32_f16(a, b0, acc[m][0], 0, 0, 0);
                acc[m][1] = __builtin_amdgcn_mfma_f32_16x16x32_f16(a, b1, acc[m][1], 0, 0, 0);
                acc[m][2] = __builtin_amdgcn_mfma_f32_16x16x32_f16(a, b2, acc[m][2], 0, 0, 0);
                acc[m][3] = __builtin_amdgcn_mfma_f32_16x16x32_f16(a, b3, acc[m][3], 0, 0, 0);
            }
        }
        // ks = 1
        {
            hf8 b0 = *(hf8*)&Bs[bR1];
            hf8 b1 = *(hf8*)&Bs[bR1 + 1024];
            hf8 b2 = *(hf8*)&Bs[bR1 + 2048];
            hf8 b3 = *(hf8*)&Bs[bR1 + 3072];
#pragma unroll
            for (int m = 0; m < 4; ++m) {
                hf8 a = *(hf8*)&As[aR1 + m * 1024];
                acc[m][0] = __builtin_amdgcn_mfma_f32_16x16x32_f16(a, b0, acc[m][0], 0, 0, 0);
                acc[m][1] = __builtin_amdgcn_mfma_f32_16x16x32_f16(a, b1, acc[m][1], 0, 0, 0);
                acc[m][2] = __builtin_amdgcn_mfma_f32_16x16x32_f16(a, b2, acc[m][2], 0, 0, 0);
                acc[m][3] = __builtin_amdgcn_mfma_f32_16x16x32_f16(a, b3, acc[m][3], 0, 0, 0);
            }
        }
        __syncthreads();                     // reads done: buffers reusable
    }

    // LEAN epilogue: per-lane top-2 over n, 16-lane butterfly top-2 merge,
    // direct global write per (strip, wc, row). No LDS (R19-proven, no spill).
    int g = lane >> 4;
#pragma unroll
    for (int m = 0; m < 4; ++m)
#pragma unroll
        for (int i = 0; i < 4; ++i) {
            float v1 = INF, v2 = INF;
            int i1 = BIGI, i2 = BIGI;
#pragma unroll
            for (int n = 0; n < 4; ++n) {
                int kcode = cb + wc * 64 + n * 16 + (lane & 15);
                float d = fmaf(-2.f, acc[m][n][i], cnorm[kcode]);
                if (d < v1) { v2 = v1; i2 = i1; v1 = d; i1 = kcode; }
                else if (d < v2) { v2 = d; i2 = kcode; }
            }
#pragma unroll
            for (int off = 1; off < 16; off <<= 1) {
                float ov1 = __shfl_xor(v1, off, 64); int oi1 = __shfl_xor(i1, off, 64);
                float ov2 = __shfl_xor(v2, off, 64); int oi2 = __shfl_xor(i2, off, 64);
                if (ov1 < v1 || (ov1 == v1 && oi1 < i1)) {
                    float tv = v1; int ti = i1;
                    v1 = ov1; i1 = oi1; ov1 = tv; oi1 = ti;
                }
                if (ov1 < v2 || (ov1 == v2 && oi1 < i2)) { v2 = ov1; i2 = oi1; }
                if (ov2 < v2 || (ov2 == v2 && oi2 < i2)) { v2 = ov2; i2 = oi2; }
            }
            if ((lane & 15) == 0) {
                int row = rb + wr * 64 + m * 16 + g * 4 + i;
                part[(size_t)(strip * 2 + wc) * NR + row] =
                    make_float4(v1, __int_as_float(i1), v2, __int_as_float(i2));
            }
        }
}

// ------------------------------------------ exact combine (one wave per row)
// 64 candidates/row (top-2 x 32 half-planes). Wave-min of estimates, then
// exact fp64 distance for every candidate within MARGIN of the best estimate
// (covers f16 estimate error, sigma~0.022); lowest-index tie-break.
__global__ __launch_bounds__(256)
void combine_exact(const float4* __restrict__ part, const float* __restrict__ f,
                   const float* __restrict__ code, int* __restrict__ idx) {
    int wv = threadIdx.x >> 6, lane = threadIdx.x & 63;
    int n = blockIdx.x * 4 + wv;
    if (n >= NR) return;
    int grp = lane >> 1, c = lane & 1;
    float4 q = part[(size_t)grp * NR + n];
    float est = c ? q.z : q.x;
    int   ci  = __float_as_int(c ? q.w : q.y);
    float be = est; int bi = ci;
#pragma unroll
    for (int off = 32; off; off >>= 1) {
        float oe = __shfl_xor(be, off, 64);
        int   oi = __shfl_xor(bi, off, 64);
        if (oe < be || (oe == be && oi < bi)) { be = oe; bi = oi; }
    }
    unsigned long long mask = __ballot(est <= be + MARGIN);
    const float* fr = f + (size_t)n * CDIM;
    float4 fa = *(const float4*)&fr[lane * 8];
    float4 fb = *(const float4*)&fr[lane * 8 + 4];
    double bd = 1.0e300; int bidx = BIGI;
    while (mask) {
        int src = __ffsll((long long)mask) - 1;
        mask &= mask - 1;
        int cand = __shfl(ci, src, 64);
        const float* cr = code + (size_t)cand * CDIM;
        float4 ca = *(const float4*)&cr[lane * 8];
        float4 cb = *(const float4*)&cr[lane * 8 + 4];
        double s = 0.0;
        s += (double)ca.x * ca.x - 2.0 * (double)fa.x * ca.x;
        s += (double)ca.y * ca.y - 2.0 * (double)fa.y * ca.y;
        s += (double)ca.z * ca.z - 2.0 * (double)fa.z * ca.z;
        s += (double)ca.w * ca.w - 2.0 * (double)fa.w * ca.w;
        s += (double)cb.x * cb.x - 2.0 * (double)fb.x * cb.x;
        s += (double)cb.y * cb.y - 2.0 * (double)fb.y * cb.y;
        s += (double)cb.z * cb.z - 2.0 * (double)fb.z * cb.z;
        s += (double)cb.w * cb.w - 2.0 * (double)fb.w * cb.w;
#pragma unroll
        for (int off = 32; off; off >>= 1) s += __shfl_down(s, off, 64);
        s = __shfl(s, 0, 64);
        if (s < bd || (s == bd && cand < bidx)) { bd = s; bidx = cand; }
    }
    if (lane == 0) idx[n] = bidx;
}

// ------------------------------------------------------------ update stage
// writef=0 (last stage): residual write-back skipped (f is dead after).
// Also emits f16 hi of the new residual when fsout != nullptr.
__global__ __launch_bounds__(256)
void vq_update(float* __restrict__ f, const float* __restrict__ code,
               const int* __restrict__ idx, float* __restrict__ xout,
               const float* __restrict__ x1p, const float* __restrict__ x2p,
               float* __restrict__ reconp, _Float16* __restrict__ fsout,
               float* __restrict__ lacc, int writef) {
    __shared__ float qt[32][33];
    __shared__ float wsum[4];
    int b = blockIdx.z, c0 = blockIdx.y * 32, h0 = blockIdx.x * 32;
    int t = threadIdx.x;
    int tx = t & 31, ty0 = t >> 5;
    float lsum = 0.f;
#pragma unroll
    for (int it = 0; it < 4; ++it) {
        int hwl = ty0 + it * 8;
        int hw = h0 + hwl;
        float qv = 0.f;
        if (hw < HWN) {
            int n = b * HWN + hw;
            size_t fo = (size_t)n * CDIM + c0 + tx;
            float fv = f[fo];
            qv = code[(size_t)idx[n] * CDIM + c0 + tx];
            float rem = fv - qv;
            if (writef) f[fo] = rem;
            lsum += rem * rem;
            if (fsout) fsout[fo] = (_Float16)rem;
        }
        qt[tx][hwl] = qv;
    }
    __syncthreads();
    {
        int hl = t & 31, cl0 = t >> 5;
#pragma unroll
        for (int it = 0; it < 4; ++it) {
            int cl = cl0 + it * 8;
            int hw = h0 + hl;
            if (hw < HWN) {
                size_t off = ((size_t)b * CDIM + c0 + cl) * HWN + hw;
                float qv = qt[cl][hl];
                xout[off] = qv;
                if (reconp) reconp[off] = qv + x1p[off] + x2p[off];
            }
        }
    }
#pragma unroll
    for (int off = 32; off; off >>= 1) lsum += __shfl_down(lsum, off);
    int lane = t & 63, w = t >> 6;
    if (lane == 0) wsum[w] = lsum;
    __syncthreads();
    if (t == 0) atomicAdd(lacc, wsum[0] + wsum[1] + wsum[2] + wsum[3]);
}

__global__ void finalize_losses(const float* __restrict__ lacc, float* __restrict__ out) {
    int t = threadIdx.x;
    if (t < 3) out[t] = 2.0f * lacc[t] / (float)ETOT;
}

// ------------------------------------------------------------------- launch

extern "C" void kernel_launch(void* const* d_in, const int* in_sizes, int n_in,
                              void* d_out, int out_size, void* d_ws, size_t ws_size,
                              hipStream_t stream) {
    (void)in_sizes; (void)n_in; (void)out_size; (void)ws_size;
    const float* head = (const float*)d_in[0];
    const float* cbs[3] = {(const float*)d_in[1], (const float*)d_in[2], (const float*)d_in[3]};
    float* out = (float*)d_out;
    char* ws = (char*)d_ws;

    size_t o_f = 0;
    size_t o_fs   = o_f   + ETOT * 4;                    // f     25.69 MB
    size_t o_cs   = o_fs  + (size_t)NR * CDIM * 2;       // fs    12.85 MB
    size_t o_part = o_cs  + (size_t)KC * CDIM * 2;       // cspl   2.10 MB
    size_t o_idx  = o_part + (size_t)NSTRIP * NR * 32;   // part   6.42 MB
    size_t o_cn   = o_idx + (size_t)NR * 4;
    size_t o_la   = o_cn  + (size_t)KC * 4;              // total ~47.1 MB (< proven 58.85)

    float*     f     = (float*)(ws + o_f);
    _Float16*  fs    = (_Float16*)(ws + o_fs);
    _Float16*  cspl  = (_Float16*)(ws + o_cs);
    float4*    part  = (float4*)(ws + o_part);
    int*       idx   = (int*)(ws + o_idx);
    float*     cnorm = (float*)(ws + o_cn);
    float*     lacc  = (float*)(ws + o_la);

    transpose_head_split<<<dim3(25, 16, 16), 256, 0, stream>>>(head, f, fs, lacc);
    for (int s = 0; s < 3; ++s) {
        split_code_norm<<<dim3(KC * 64 / 256), 256, 0, stream>>>(cbs[s], cspl, cnorm);
        argmin_fast<<<dim3(784), 512, 0, stream>>>(fs, cspl, cnorm, part);
        combine_exact<<<dim3(NR / 4), 256, 0, stream>>>(part, f, cbs[s], idx);
        float* xout   = out + (size_t)s * ETOT;
        float* reconp = (s == 2) ? out + 3 * ETOT + 3 : nullptr;
        _Float16* fsout = (s < 2) ? fs : nullptr;
        vq_update<<<dim3(25, 16, 16), 256, 0, stream>>>(f, cbs[s], idx, xout,
                                                        out, out + ETOT, reconp,
                                                        fsout, lacc + s, (s < 2) ? 1 : 0);
    }
    finalize_losses<<<1, 64, 0, stream>>>(lacc, out + 3 * ETOT);
}

// Round 22
// 518.305 us; speedup vs baseline: 1.8987x; 1.8987x over previous
//
#include <hip/hip_runtime.h>
#include <cstddef>

#define BB    16
#define CDIM  512
#define HWN   784
#define KC    2048
#define NR    (BB*HWN)                  // 12544 rows (= 98*128)
#define ETOT  ((size_t)BB*CDIM*HWN)     // 6422528 elements per tensor
#define NSTRIP 16                       // code strips of 128 (32 half-planes)
#define MARGIN 0.5f                     // exact-recheck margin (~22 sigma)
#define INF   3.0e38f
#define BIGI  0x7fffffff

typedef _Float16 hf8 __attribute__((ext_vector_type(8)));
typedef float f32x4 __attribute__((ext_vector_type(4)));

__device__ __forceinline__ void gload_lds16(const void* g, void* l) {
    __builtin_amdgcn_global_load_lds((const __attribute__((address_space(1))) void*)g,
                                     (__attribute__((address_space(3))) void*)l, 16, 0, 0);
}

// ---------------------------------------------------------------- utilities

// head (B,C,HW) -> f rows (fp32) AND fs rows (f16 hi only); zeroes lacc.
__global__ __launch_bounds__(256)
void transpose_head_split(const float* __restrict__ head, float* __restrict__ f,
                          _Float16* __restrict__ fs, float* __restrict__ lacc) {
    __shared__ float tile[32][33];
    int b = blockIdx.z, c0 = blockIdx.y * 32, h0 = blockIdx.x * 32;
    int t = threadIdx.x;
    if (b == 0 && blockIdx.y == 0 && blockIdx.x == 0 && t < 3) lacc[t] = 0.f;
    const float* src = head + (size_t)b * CDIM * HWN;
    {
        int hl = t & 31, cl0 = t >> 5;
#pragma unroll
        for (int it = 0; it < 4; ++it) {
            int cl = cl0 + it * 8;
            int hw = h0 + hl;
            if (hw < HWN) tile[cl][hl] = src[(size_t)(c0 + cl) * HWN + hw];
        }
    }
    __syncthreads();
    float* dst = f + (size_t)b * HWN * CDIM;
    _Float16* dsts = fs + (size_t)b * HWN * CDIM;
    {
        int cl = t & 31, hl0 = t >> 5;
#pragma unroll
        for (int it = 0; it < 4; ++it) {
            int hl = hl0 + it * 8;
            int hw = h0 + hl;
            if (hw < HWN) {
                float v = tile[cl][hl];
                dst[(size_t)hw * CDIM + c0 + cl] = v;
                dsts[(size_t)hw * CDIM + c0 + cl] = (_Float16)v;
            }
        }
    }
}

// codebook fp32 [K][512] -> f16 hi [K][512] + ||row||^2 (one wave per row)
__global__ __launch_bounds__(256)
void split_code_norm(const float* __restrict__ src, _Float16* __restrict__ dst,
                     float* __restrict__ cnorm) {
    int tid = blockIdx.x * 256 + threadIdx.x;        // 8 elems per thread
    int row = tid >> 6, c8 = (tid & 63) * 8;
    const float* p = src + (size_t)row * CDIM + c8;
    float4 v0 = *(const float4*)p, v1 = *(const float4*)(p + 4);
    hf8 hi;
    float x[8] = {v0.x, v0.y, v0.z, v0.w, v1.x, v1.y, v1.z, v1.w};
    float s = 0.f;
#pragma unroll
    for (int j = 0; j < 8; ++j) {
        hi[j] = (_Float16)x[j];
        s += x[j] * x[j];
    }
    *(hf8*)&dst[(size_t)row * CDIM + c8] = hi;
#pragma unroll
    for (int off = 32; off; off >>= 1) s += __shfl_down(s, off);
    if ((threadIdx.x & 63) == 0) cnorm[row] = s;
}

// --------------------------------------------- MFMA coarse argmin (f16 hi, K=512)
// 128 rows x 128 codes per block, 256 threads = 4 waves (2x2 of 64x64 — the
// EXACT R19 wave layout/formulas, tile halved). Single-buffered A(16KB) +
// B(16KB) = 32KB LDS, serial 2-barrier frame (R6/R21-proven hazards).
// launch_bounds(256,4) -> 128-reg budget: acc(64)+addressing fits, NO spill
// (R21's failure). Runtime occupancy ~16 waves/CU (50%) vs R19's 12.
// Grid 1568 (=8*196, XCD-swizzled). Emits lean top-2 per (strip, wc, row).
__global__ __launch_bounds__(256, 4)
void argmin_fast(const _Float16* __restrict__ fs, const _Float16* __restrict__ cs,
                 const float* __restrict__ cnorm, float4* __restrict__ part) {
    __shared__ _Float16 As[128 * 64];    // 16 KB
    __shared__ _Float16 Bs[128 * 64];    // 16 KB

    int t = threadIdx.x;
    int lane = t & 63, w = t >> 6;
    int wr = w >> 1, wc = w & 1;

    // XCD swizzle: nwg = 1568 = 8*196
    int lin = blockIdx.x;
    int swz = (lin & 7) * 196 + (lin >> 3);
    int strip = swz & 15, rowtile = swz >> 4;    // rowtile 0..97
    int rb = rowtile * 128, cb = strip * 128;

    // staging: thread t stages granules {t, 256+t, 512+t, 768+t} of each
    // operand tile (granule g: row = g>>3, col-granule = g&7 = t&7).
    // Source col-granule XOR-swizzled by row&7 (= (t>>3)&7, invariant under
    // +32 row steps). LDS dest linear at g*8 (R18/R19-verified pattern).
    int srow = t >> 3;
    int sgx = (t & 7) ^ (srow & 7);
    const _Float16* pA0 = fs + (size_t)(rb + srow) * CDIM + sgx * 8;
    const _Float16* pA1 = fs + (size_t)(rb + 32 + srow) * CDIM + sgx * 8;
    const _Float16* pA2 = fs + (size_t)(rb + 64 + srow) * CDIM + sgx * 8;
    const _Float16* pA3 = fs + (size_t)(rb + 96 + srow) * CDIM + sgx * 8;
    const _Float16* pB0 = cs + (size_t)(cb + srow) * CDIM + sgx * 8;
    const _Float16* pB1 = cs + (size_t)(cb + 32 + srow) * CDIM + sgx * 8;
    const _Float16* pB2 = cs + (size_t)(cb + 64 + srow) * CDIM + sgx * 8;
    const _Float16* pB3 = cs + (size_t)(cb + 96 + srow) * CDIM + sgx * 8;
    int dd = t * 8;

    // fragment reads: row r wants logical granule ks*4+(lane>>4) at physical
    // granule ^(r&7); (r&7)==(lane&7) since 16 | row-steps (R18/R19-verified).
    int g0 = (lane >> 4) ^ (lane & 7);
    int g1 = g0 ^ 4;
    int aR0 = (wr * 64 + (lane & 15)) * 64 + g0 * 8;
    int aR1 = (wr * 64 + (lane & 15)) * 64 + g1 * 8;
    int bR0 = (wc * 64 + (lane & 15)) * 64 + g0 * 8;
    int bR1 = (wc * 64 + (lane & 15)) * 64 + g1 * 8;

    f32x4 acc[4][4];
#pragma unroll
    for (int m = 0; m < 4; ++m)
#pragma unroll
        for (int n = 0; n < 4; ++n) acc[m][n] = (f32x4)0.f;

    for (int kk = 0; kk < 8; ++kk) {
        int ko = kk * 64;
        // stage chunk kk (prev end-barrier: all waves done reading kk-1)
        gload_lds16(pA0 + ko, &As[0 * 2048 + dd]);
        gload_lds16(pA1 + ko, &As[1 * 2048 + dd]);
        gload_lds16(pA2 + ko, &As[2 * 2048 + dd]);
        gload_lds16(pA3 + ko, &As[3 * 2048 + dd]);
        gload_lds16(pB0 + ko, &Bs[0 * 2048 + dd]);
        gload_lds16(pB1 + ko, &Bs[1 * 2048 + dd]);
        gload_lds16(pB2 + ko, &Bs[2 * 2048 + dd]);
        gload_lds16(pB3 + ko, &Bs[3 * 2048 + dd]);
        __syncthreads();                     // drains vmcnt: chunk kk resident
        // ks = 0
        {
            hf8 b0 = *(hf8*)&Bs[bR0];
            hf8 b1 = *(hf8*)&Bs[bR0 + 1024];
            hf8 b2 = *(hf8*)&Bs[bR0 + 2048];
            hf8 b3 = *(hf8*)&Bs[bR0 + 3072];
#pragma unroll
            for (int m = 0; m < 4; ++m) {
                hf8 a = *(hf8*)&As[aR0 + m * 1024];
                acc[m][0] = __builtin_amdgcn_mfma_f32_16x16x32_f16(a, b0, acc[m][0], 0, 0, 0);
                acc[m][1] = __builtin_amdgcn_mfma_f32_16x16x32_f16(a, b1, acc[m][1], 0, 0, 0);
                acc[m][2] = __builtin_amdgcn_mfma_f32_16x16x32_f16(a, b2, acc[m][2], 0, 0, 0);
                acc[m][3] = __builtin_amdgcn_mfma_f32_16x16x32_f16(a, b3, acc[m][3], 0, 0, 0);
            }
        }
        // ks = 1
        {
            hf8 b0 = *(hf8*)&Bs[bR1];
            hf8 b1 = *(hf8*)&Bs[bR1 + 1024];
            hf8 b2 = *(hf8*)&Bs[bR1 + 2048];
            hf8 b3 = *(hf8*)&Bs[bR1 + 3072];
#pragma unroll
            for (int m = 0; m < 4; ++m) {
                hf8 a = *(hf8*)&As[aR1 + m * 1024];
                acc[m][0] = __builtin_amdgcn_mfma_f32_16x16x32_f16(a, b0, acc[m][0], 0, 0, 0);
                acc[m][1] = __builtin_amdgcn_mfma_f32_16x16x32_f16(a, b1, acc[m][1], 0, 0, 0);
                acc[m][2] = __builtin_amdgcn_mfma_f32_16x16x32_f16(a, b2, acc[m][2], 0, 0, 0);
                acc[m][3] = __builtin_amdgcn_mfma_f32_16x16x32_f16(a, b3, acc[m][3], 0, 0, 0);
            }
        }
        __syncthreads();                     // reads done: buffers reusable
    }

    // LEAN epilogue (R19-proven): per-lane top-2 over n, 16-lane butterfly,
    // direct global write per (strip, wc, row). Each (row, wc) is written by
    // exactly one wave (2x2 layout over 128 rows).
    int g = lane >> 4;
#pragma unroll
    for (int m = 0; m < 4; ++m)
#pragma unroll
        for (int i = 0; i < 4; ++i) {
            float v1 = INF, v2 = INF;
            int i1 = BIGI, i2 = BIGI;
#pragma unroll
            for (int n = 0; n < 4; ++n) {
                int kcode = cb + wc * 64 + n * 16 + (lane & 15);
                float d = fmaf(-2.f, acc[m][n][i], cnorm[kcode]);
                if (d < v1) { v2 = v1; i2 = i1; v1 = d; i1 = kcode; }
                else if (d < v2) { v2 = d; i2 = kcode; }
            }
#pragma unroll
            for (int off = 1; off < 16; off <<= 1) {
                float ov1 = __shfl_xor(v1, off, 64); int oi1 = __shfl_xor(i1, off, 64);
                float ov2 = __shfl_xor(v2, off, 64); int oi2 = __shfl_xor(i2, off, 64);
                if (ov1 < v1 || (ov1 == v1 && oi1 < i1)) {
                    float tv = v1; int ti = i1;
                    v1 = ov1; i1 = oi1; ov1 = tv; oi1 = ti;
                }
                if (ov1 < v2 || (ov1 == v2 && oi1 < i2)) { v2 = ov1; i2 = oi1; }
                if (ov2 < v2 || (ov2 == v2 && oi2 < i2)) { v2 = ov2; i2 = oi2; }
            }
            if ((lane & 15) == 0) {
                int row = rb + wr * 64 + m * 16 + g * 4 + i;
                part[(size_t)(strip * 2 + wc) * NR + row] =
                    make_float4(v1, __int_as_float(i1), v2, __int_as_float(i2));
            }
        }
}

// ------------------------------------------ exact combine (one wave per row)
// 64 candidates/row (top-2 x 32 half-planes). Wave-min of estimates, then
// exact fp64 distance for every candidate within MARGIN of the best estimate
// (covers f16 estimate error, sigma~0.022); lowest-index tie-break.
__global__ __launch_bounds__(256)
void combine_exact(const float4* __restrict__ part, const float* __restrict__ f,
                   const float* __restrict__ code, int* __restrict__ idx) {
    int wv = threadIdx.x >> 6, lane = threadIdx.x & 63;
    int n = blockIdx.x * 4 + wv;
    if (n >= NR) return;
    int grp = lane >> 1, c = lane & 1;
    float4 q = part[(size_t)grp * NR + n];
    float est = c ? q.z : q.x;
    int   ci  = __float_as_int(c ? q.w : q.y);
    float be = est; int bi = ci;
#pragma unroll
    for (int off = 32; off; off >>= 1) {
        float oe = __shfl_xor(be, off, 64);
        int   oi = __shfl_xor(bi, off, 64);
        if (oe < be || (oe == be && oi < bi)) { be = oe; bi = oi; }
    }
    unsigned long long mask = __ballot(est <= be + MARGIN);
    const float* fr = f + (size_t)n * CDIM;
    float4 fa = *(const float4*)&fr[lane * 8];
    float4 fb = *(const float4*)&fr[lane * 8 + 4];
    double bd = 1.0e300; int bidx = BIGI;
    while (mask) {
        int src = __ffsll((long long)mask) - 1;
        mask &= mask - 1;
        int cand = __shfl(ci, src, 64);
        const float* cr = code + (size_t)cand * CDIM;
        float4 ca = *(const float4*)&cr[lane * 8];
        float4 cb = *(const float4*)&cr[lane * 8 + 4];
        double s = 0.0;
        s += (double)ca.x * ca.x - 2.0 * (double)fa.x * ca.x;
        s += (double)ca.y * ca.y - 2.0 * (double)fa.y * ca.y;
        s += (double)ca.z * ca.z - 2.0 * (double)fa.z * ca.z;
        s += (double)ca.w * ca.w - 2.0 * (double)fa.w * ca.w;
        s += (double)cb.x * cb.x - 2.0 * (double)fb.x * cb.x;
        s += (double)cb.y * cb.y - 2.0 * (double)fb.y * cb.y;
        s += (double)cb.z * cb.z - 2.0 * (double)fb.z * cb.z;
        s += (double)cb.w * cb.w - 2.0 * (double)fb.w * cb.w;
#pragma unroll
        for (int off = 32; off; off >>= 1) s += __shfl_down(s, off, 64);
        s = __shfl(s, 0, 64);
        if (s < bd || (s == bd && cand < bidx)) { bd = s; bidx = cand; }
    }
    if (lane == 0) idx[n] = bidx;
}

// ------------------------------------------------------------ update stage
// writef=0 (last stage): residual write-back skipped (f is dead after).
// Also emits f16 hi of the new residual when fsout != nullptr.
__global__ __launch_bounds__(256)
void vq_update(float* __restrict__ f, const float* __restrict__ code,
               const int* __restrict__ idx, float* __restrict__ xout,
               const float* __restrict__ x1p, const float* __restrict__ x2p,
               float* __restrict__ reconp, _Float16* __restrict__ fsout,
               float* __restrict__ lacc, int writef) {
    __shared__ float qt[32][33];
    __shared__ float wsum[4];
    int b = blockIdx.z, c0 = blockIdx.y * 32, h0 = blockIdx.x * 32;
    int t = threadIdx.x;
    int tx = t & 31, ty0 = t >> 5;
    float lsum = 0.f;
#pragma unroll
    for (int it = 0; it < 4; ++it) {
        int hwl = ty0 + it * 8;
        int hw = h0 + hwl;
        float qv = 0.f;
        if (hw < HWN) {
            int n = b * HWN + hw;
            size_t fo = (size_t)n * CDIM + c0 + tx;
            float fv = f[fo];
            qv = code[(size_t)idx[n] * CDIM + c0 + tx];
            float rem = fv - qv;
            if (writef) f[fo] = rem;
            lsum += rem * rem;
            if (fsout) fsout[fo] = (_Float16)rem;
        }
        qt[tx][hwl] = qv;
    }
    __syncthreads();
    {
        int hl = t & 31, cl0 = t >> 5;
#pragma unroll
        for (int it = 0; it < 4; ++it) {
            int cl = cl0 + it * 8;
            int hw = h0 + hl;
            if (hw < HWN) {
                size_t off = ((size_t)b * CDIM + c0 + cl) * HWN + hw;
                float qv = qt[cl][hl];
                xout[off] = qv;
                if (reconp) reconp[off] = qv + x1p[off] + x2p[off];
            }
        }
    }
#pragma unroll
    for (int off = 32; off; off >>= 1) lsum += __shfl_down(lsum, off);
    int lane = t & 63, w = t >> 6;
    if (lane == 0) wsum[w] = lsum;
    __syncthreads();
    if (t == 0) atomicAdd(lacc, wsum[0] + wsum[1] + wsum[2] + wsum[3]);
}

__global__ void finalize_losses(const float* __restrict__ lacc, float* __restrict__ out) {
    int t = threadIdx.x;
    if (t < 3) out[t] = 2.0f * lacc[t] / (float)ETOT;
}

// ------------------------------------------------------------------- launch

extern "C" void kernel_launch(void* const* d_in, const int* in_sizes, int n_in,
                              void* d_out, int out_size, void* d_ws, size_t ws_size,
                              hipStream_t stream) {
    (void)in_sizes; (void)n_in; (void)out_size; (void)ws_size;
    const float* head = (const float*)d_in[0];
    const float* cbs[3] = {(const float*)d_in[1], (const float*)d_in[2], (const float*)d_in[3]};
    float* out = (float*)d_out;
    char* ws = (char*)d_ws;

    size_t o_f = 0;
    size_t o_fs   = o_f   + ETOT * 4;                    // f     25.69 MB
    size_t o_cs   = o_fs  + (size_t)NR * CDIM * 2;       // fs    12.85 MB
    size_t o_part = o_cs  + (size_t)KC * CDIM * 2;       // cspl   2.10 MB
    size_t o_idx  = o_part + (size_t)NSTRIP * NR * 32;   // part   6.42 MB
    size_t o_cn   = o_idx + (size_t)NR * 4;
    size_t o_la   = o_cn  + (size_t)KC * 4;              // total ~47.1 MB (< proven 58.85)

    float*     f     = (float*)(ws + o_f);
    _Float16*  fs    = (_Float16*)(ws + o_fs);
    _Float16*  cspl  = (_Float16*)(ws + o_cs);
    float4*    part  = (float4*)(ws + o_part);
    int*       idx   = (int*)(ws + o_idx);
    float*     cnorm = (float*)(ws + o_cn);
    float*     lacc  = (float*)(ws + o_la);

    transpose_head_split<<<dim3(25, 16, 16), 256, 0, stream>>>(head, f, fs, lacc);
    for (int s = 0; s < 3; ++s) {
        split_code_norm<<<dim3(KC * 64 / 256), 256, 0, stream>>>(cbs[s], cspl, cnorm);
        argmin_fast<<<dim3(1568), 256, 0, stream>>>(fs, cspl, cnorm, part);
        combine_exact<<<dim3(NR / 4), 256, 0, stream>>>(part, f, cbs[s], idx);
        float* xout   = out + (size_t)s * ETOT;
        float* reconp = (s == 2) ? out + 3 * ETOT + 3 : nullptr;
        _Float16* fsout = (s < 2) ? fs : nullptr;
        vq_update<<<dim3(25, 16, 16), 256, 0, stream>>>(f, cbs[s], idx, xout,
                                                        out, out + ETOT, reconp,
                                                        fsout, lacc + s, (s < 2) ? 1 : 0);
    }
    finalize_losses<<<1, 64, 0, stream>>>(lacc, out + 3 * ETOT);
}